// Round 1
// baseline (565.598 us; speedup 1.0000x reference)
//
#include <hip/hip_runtime.h>
#include <stdint.h>

#define Bn 16384
#define Dn 64
#define Hn 256

typedef short bf16x8 __attribute__((ext_vector_type(8)));
typedef float f32x4 __attribute__((ext_vector_type(4)));

__device__ __forceinline__ unsigned f2bf1(float f) {
  unsigned u = __float_as_uint(f);
  return (u + 0x7FFFu + ((u >> 16) & 1u)) >> 16;   // RNE to bf16
}

// ---------- pack W2 (fp32 [D][H][H]) into MFMA B-fragment-linear bf16 ----------
// layout: [d][kk(8)][nj(16)][lane(64)][8 bf16]; lane holds B[k=kk*32+(lane>>4)*8+b][n=nj*16+(lane&15)]
__global__ __launch_bounds__(256) void pack_w2(const float* __restrict__ W2,
                                               unsigned short* __restrict__ Bp) {
  int g = blockIdx.x * 4 + (threadIdx.x >> 6);   // 8192 units
  int lane = threadIdx.x & 63;
  int d  = g >> 7;
  int kk = (g >> 4) & 7;
  int nj = g & 15;
  int k0 = kk * 32 + ((lane >> 4) << 3);
  int n  = nj * 16 + (lane & 15);
  const float* src = W2 + ((size_t)d * Hn + k0) * Hn + n;
  unsigned t[8];
  #pragma unroll
  for (int b = 0; b < 8; ++b) t[b] = f2bf1(src[(size_t)b * Hn]);
  uint4 w;
  w.x = t[0] | (t[1] << 16);
  w.y = t[2] | (t[3] << 16);
  w.z = t[4] | (t[5] << 16);
  w.w = t[6] | (t[7] << 16);
  size_t off = (((size_t)g) * 64 + lane) * 8;    // elements
  *(uint4*)(Bp + off) = w;
}

// ---------- transpose small tail weights for coalesced reads ----------
__global__ __launch_bounds__(256) void prep_t(
    const float* __restrict__ Wq, const float* __restrict__ Wk,
    const float* __restrict__ Wc1, const float* __restrict__ Ws,
    float* __restrict__ WqT, float* __restrict__ WkT,
    float* __restrict__ Wc1T, float* __restrict__ WsT) {
  int t = blockIdx.x * 256 + threadIdx.x;   // 16384
  int h = t >> 6, dd = t & 63;
  WqT[dd * 256 + h]  = Wq[h * 64 + dd];
  WkT[dd * 256 + h]  = Wk[h * 64 + dd];
  Wc1T[dd * 256 + h] = Wc1[h * 64 + dd];
  WsT[h * 64 + dd]   = Ws[dd * 256 + h];
}

// ---------- main fused kernel: a1 = relu(x*W1+b1) -> GEMM vs W2 -> relu(+b2) -> dot W3 -> h_cat ----------
__global__ __launch_bounds__(512, 1) void gemm_hcat(
    const float* __restrict__ x, const float* __restrict__ W1,
    const float* __restrict__ b1, const float* __restrict__ b2,
    const float* __restrict__ W3, const float* __restrict__ b3,
    const unsigned short* __restrict__ Bp, float* __restrict__ hcT) {
  __shared__ char a1s[65536];    // a1 tile [128 rows][256 bf16], row stride 512B, XOR-swizzled
  __shared__ char Bsts[65536];   // W2 stage, 2 x 32KB (BK=64); reused as reduce buffer P

  int bid = blockIdx.x;
  int swz = (bid & 7) * 1024 + (bid >> 3);   // bijective XCD swizzle (8192 = 8*1024)
  int d = swz >> 7;
  int m0 = (swz & 127) << 7;

  int tid = threadIdx.x;
  int lane = tid & 63;
  int wid = tid >> 6;
  int wm = wid >> 2, wn = wid & 3;           // 2M x 4N waves, 64x64 per wave

  const unsigned short* BpD = Bp + (size_t)d * 65536;

  // prologue: issue stage 0 -> buf 0 (overlaps with a1 compute below)
  #pragma unroll
  for (int c = 0; c < 4; ++c) {
    const void* g = (const void*)(BpD + c * 4096 + tid * 8);
    void* l = (void*)(Bsts + c * 8192 + tid * 16);
    __builtin_amdgcn_global_load_lds((const __attribute__((address_space(1))) void*)g,
                                     (__attribute__((address_space(3))) void*)l, 16, 0, 0);
  }

  // compute a1 tile into LDS (bf16, swizzled)
  {
    int r = tid >> 2;
    int q = tid & 3;
    float xv = x[(size_t)(m0 + r) * Dn + d];
    const float4* W1v = (const float4*)(W1 + d * Hn);
    const float4* b1v = (const float4*)(b1 + d * Hn);
    char* rowp = a1s + r * 512;
    int sw = (r & 7) << 4;
    #pragma unroll
    for (int i = 0; i < 16; ++i) {
      int h = q * 64 + i * 4;
      float4 w = W1v[h >> 2];
      float4 bb = b1v[h >> 2];
      unsigned v0 = f2bf1(fmaxf(fmaf(xv, w.x, bb.x), 0.f));
      unsigned v1 = f2bf1(fmaxf(fmaf(xv, w.y, bb.y), 0.f));
      unsigned v2 = f2bf1(fmaxf(fmaf(xv, w.z, bb.z), 0.f));
      unsigned v3 = f2bf1(fmaxf(fmaf(xv, w.w, bb.w), 0.f));
      uint2 pk;
      pk.x = v0 | (v1 << 16);
      pk.y = v2 | (v3 << 16);
      *(uint2*)(rowp + ((h * 2) ^ sw)) = pk;
    }
  }

  f32x4 acc[4][4] = {};

  #pragma unroll
  for (int s = 0; s < 4; ++s) {
    asm volatile("s_waitcnt vmcnt(0)" ::: "memory");
    __syncthreads();
    if (s < 3) {   // issue next stage before compute (2-phase overlap)
      const unsigned short* sb = BpD + (s + 1) * 16384;
      char* db = Bsts + ((s + 1) & 1) * 32768;
      #pragma unroll
      for (int c = 0; c < 4; ++c) {
        const void* g = (const void*)(sb + c * 4096 + tid * 8);
        void* l = (void*)(db + c * 8192 + tid * 16);
        __builtin_amdgcn_global_load_lds((const __attribute__((address_space(1))) void*)g,
                                         (__attribute__((address_space(3))) void*)l, 16, 0, 0);
      }
    }
    const char* bufp = Bsts + (s & 1) * 32768;
    #pragma unroll
    for (int kl = 0; kl < 2; ++kl) {
      int kk = s * 2 + kl;
      bf16x8 af[4], bfr[4];
      #pragma unroll
      for (int mi = 0; mi < 4; ++mi) {
        int row = wm * 64 + mi * 16 + (lane & 15);
        int kb = (kk * 32 + ((lane >> 4) << 3)) * 2;
        af[mi] = *(const bf16x8*)(a1s + row * 512 + (kb ^ ((row & 7) << 4)));
      }
      #pragma unroll
      for (int nj = 0; nj < 4; ++nj) {
        int njg = wn * 4 + nj;
        bfr[nj] = *(const bf16x8*)(bufp + ((kl * 16 + njg) * 64 + lane) * 16);
      }
      #pragma unroll
      for (int mi = 0; mi < 4; ++mi)
        #pragma unroll
        for (int nj = 0; nj < 4; ++nj)
          acc[mi][nj] = __builtin_amdgcn_mfma_f32_16x16x32_bf16(af[mi], bfr[nj], acc[mi][nj], 0, 0, 0);
    }
  }

  __syncthreads();
  float* P = (float*)Bsts;   // [4 wn][128 rows]
  {
    const float* b2d = b2 + d * Hn;
    const float* W3d = W3 + d * Hn;
    float bv[4], wv[4];
    #pragma unroll
    for (int nj = 0; nj < 4; ++nj) {
      int col = (wn * 4 + nj) * 16 + (lane & 15);
      bv[nj] = b2d[col];
      wv[nj] = W3d[col];
    }
    #pragma unroll
    for (int mi = 0; mi < 4; ++mi) {
      #pragma unroll
      for (int i = 0; i < 4; ++i) {
        float sv = 0.f;
        #pragma unroll
        for (int nj = 0; nj < 4; ++nj)
          sv += fmaxf(acc[mi][nj][i] + bv[nj], 0.f) * wv[nj];
        sv += __shfl_xor(sv, 1);
        sv += __shfl_xor(sv, 2);
        sv += __shfl_xor(sv, 4);
        sv += __shfl_xor(sv, 8);
        if ((lane & 15) == 0) {
          int rloc = wm * 64 + mi * 16 + ((lane >> 4) << 2) + i;
          P[wn * 128 + rloc] = sv;
        }
      }
    }
  }
  __syncthreads();
  if (tid < 128) {
    float hv = P[tid] + P[128 + tid] + P[256 + tid] + P[384 + tid] + b3[d];
    hcT[(size_t)d * Bn + m0 + tid] = hv;   // h_cat stored [D][B] for coalesced writes
  }
}

// ---------- tail: attention fusion + cross MLP + g_func, one wave per row ----------
__global__ __launch_bounds__(256) void fused_tail(
    const float* __restrict__ hcT, const float* __restrict__ WqT,
    const float* __restrict__ bq, const float* __restrict__ WkT,
    const float* __restrict__ bk, const float* __restrict__ WsT,
    const float* __restrict__ bs, const float* __restrict__ Wc1T,
    const float* __restrict__ bc1, const float* __restrict__ Wc2,
    const float* __restrict__ bc2, const float* __restrict__ Wg1,
    const float* __restrict__ bg1, const float* __restrict__ Wg2,
    const float* __restrict__ bg2, float* __restrict__ out) {
  __shared__ float hcs[4][64];
  __shared__ float ts[4][256];
  int wid = threadIdx.x >> 6;
  int lane = threadIdx.x & 63;
  int row = blockIdx.x * 4 + wid;
  float hc = hcT[(size_t)lane * Bn + row];   // lane <-> feature d
  hcs[wid][lane] = hc;
  asm volatile("s_waitcnt lgkmcnt(0)" ::: "memory");
  float qv[4], kv[4], cv[4];
  #pragma unroll
  for (int j = 0; j < 4; ++j) {
    int h = lane + 64 * j;
    qv[j] = bq[h]; kv[j] = bk[h]; cv[j] = bc1[h];
  }
  for (int d2 = 0; d2 < 64; ++d2) {
    float hv = hcs[wid][d2];
    #pragma unroll
    for (int j = 0; j < 4; ++j) {
      int h = lane + 64 * j;
      qv[j] = fmaf(WqT[d2 * 256 + h], hv, qv[j]);
      kv[j] = fmaf(WkT[d2 * 256 + h], hv, kv[j]);
      cv[j] = fmaf(Wc1T[d2 * 256 + h], hv, cv[j]);
    }
  }
  #pragma unroll
  for (int j = 0; j < 4; ++j) ts[wid][lane + 64 * j] = tanhf(qv[j] * kv[j]);
  asm volatile("s_waitcnt lgkmcnt(0)" ::: "memory");
  float sc = bs[lane];
  for (int h2 = 0; h2 < 256; ++h2) sc = fmaf(WsT[h2 * 64 + lane], ts[wid][h2], sc);
  // softmax over the 64 features (one per lane)
  float mx = sc;
  #pragma unroll
  for (int off = 1; off < 64; off <<= 1) mx = fmaxf(mx, __shfl_xor(mx, off));
  float e = __expf(sc - mx);
  float se = e;
  #pragma unroll
  for (int off = 1; off < 64; off <<= 1) se += __shfl_xor(se, off);
  float wgt = hc * (e / se);
  #pragma unroll
  for (int off = 1; off < 64; off <<= 1) wgt += __shfl_xor(wgt, off);
  // cross MLP
  float cp = 0.f;
  #pragma unroll
  for (int j = 0; j < 4; ++j) {
    int h = lane + 64 * j;
    cp = fmaf(fmaxf(cv[j], 0.f), Wc2[h], cp);
  }
  #pragma unroll
  for (int off = 1; off < 64; off <<= 1) cp += __shfl_xor(cp, off);
  float comb = wgt + cp + bc2[0];
  // g_func
  float fp = 0.f;
  #pragma unroll
  for (int j = 0; j < 4; ++j) {
    int h = lane + 64 * j;
    fp = fmaf(fmaxf(fmaf(comb, Wg1[h], bg1[h]), 0.f), Wg2[h], fp);
  }
  #pragma unroll
  for (int off = 1; off < 64; off <<= 1) fp += __shfl_xor(fp, off);
  if (lane == 0) out[row] = fp + bg2[0];
}

extern "C" void kernel_launch(void* const* d_in, const int* in_sizes, int n_in,
                              void* d_out, int out_size, void* d_ws, size_t ws_size,
                              hipStream_t stream) {
  const float* x   = (const float*)d_in[0];
  const float* W1  = (const float*)d_in[1];
  const float* b1  = (const float*)d_in[2];
  const float* W2  = (const float*)d_in[3];
  const float* b2  = (const float*)d_in[4];
  const float* W3  = (const float*)d_in[5];
  const float* b3  = (const float*)d_in[6];
  const float* Wq  = (const float*)d_in[7];
  const float* bq  = (const float*)d_in[8];
  const float* Wk  = (const float*)d_in[9];
  const float* bk  = (const float*)d_in[10];
  const float* Ws  = (const float*)d_in[11];
  const float* bs  = (const float*)d_in[12];
  const float* Wc1 = (const float*)d_in[13];
  const float* bc1 = (const float*)d_in[14];
  const float* Wc2 = (const float*)d_in[15];
  const float* bc2 = (const float*)d_in[16];
  const float* Wg1 = (const float*)d_in[17];
  const float* bg1 = (const float*)d_in[18];
  const float* Wg2 = (const float*)d_in[19];
  const float* bg2 = (const float*)d_in[20];

  unsigned short* Bp = (unsigned short*)d_ws;               // 8,388,608 B
  float* hcT  = (float*)((char*)d_ws + 8388608);            // 4,194,304 B
  float* WqT  = (float*)((char*)d_ws + 12582912);
  float* WkT  = WqT + 16384;
  float* Wc1T = WkT + 16384;
  float* WsT  = Wc1T + 16384;

  pack_w2<<<2048, 256, 0, stream>>>(W2, Bp);
  prep_t<<<64, 256, 0, stream>>>(Wq, Wk, Wc1, Ws, WqT, WkT, Wc1T, WsT);
  gemm_hcat<<<8192, 512, 0, stream>>>(x, W1, b1, b2, W3, b3, Bp, hcT);
  fused_tail<<<4096, 256, 0, stream>>>(hcT, WqT, bq, WkT, bk, WsT, bs, Wc1T, bc1,
                                       Wc2, bc2, Wg1, bg1, Wg2, bg2, (float*)d_out);
}

// Round 2
// 320.987 us; speedup vs baseline: 1.7621x; 1.7621x over previous
//
#include <hip/hip_runtime.h>
#include <stdint.h>

#define Bn 16384
#define Dn 64
#define Hn 256

typedef short bf16x8 __attribute__((ext_vector_type(8)));
typedef float f32x4 __attribute__((ext_vector_type(4)));

__device__ __forceinline__ unsigned f2bf1(float f) {
  unsigned u = __float_as_uint(f);
  return (u + 0x7FFFu + ((u >> 16) & 1u)) >> 16;   // RNE to bf16
}

// ---------- pack W2 (fp32 [D][H][H]) into MFMA B-fragment-linear bf16 ----------
// layout: [d][kk(8)][nj(16)][lane(64)][8 bf16]; lane holds B[k=kk*32+(lane>>4)*8+b][n=nj*16+(lane&15)]
__global__ __launch_bounds__(256) void pack_w2(const float* __restrict__ W2,
                                               unsigned short* __restrict__ Bp) {
  int g = blockIdx.x * 4 + (threadIdx.x >> 6);   // 8192 units
  int lane = threadIdx.x & 63;
  int d  = g >> 7;
  int kk = (g >> 4) & 7;
  int nj = g & 15;
  int k0 = kk * 32 + ((lane >> 4) << 3);
  int n  = nj * 16 + (lane & 15);
  const float* src = W2 + ((size_t)d * Hn + k0) * Hn + n;
  unsigned t[8];
  #pragma unroll
  for (int b = 0; b < 8; ++b) t[b] = f2bf1(src[(size_t)b * Hn]);
  uint4 w;
  w.x = t[0] | (t[1] << 16);
  w.y = t[2] | (t[3] << 16);
  w.z = t[4] | (t[5] << 16);
  w.w = t[6] | (t[7] << 16);
  size_t off = (((size_t)g) * 64 + lane) * 8;    // elements
  *(uint4*)(Bp + off) = w;
}

// ---------- transpose small tail weights for coalesced reads ----------
__global__ __launch_bounds__(256) void prep_t(
    const float* __restrict__ Wq, const float* __restrict__ Wk,
    const float* __restrict__ Wc1, const float* __restrict__ Ws,
    float* __restrict__ WqT, float* __restrict__ WkT,
    float* __restrict__ Wc1T, float* __restrict__ WsT) {
  int t = blockIdx.x * 256 + threadIdx.x;   // 16384
  int h = t >> 6, dd = t & 63;
  WqT[dd * 256 + h]  = Wq[h * 64 + dd];
  WkT[dd * 256 + h]  = Wk[h * 64 + dd];
  Wc1T[dd * 256 + h] = Wc1[h * 64 + dd];
  WsT[h * 64 + dd]   = Ws[dd * 256 + h];
}

// ---------- main fused kernel ----------
// BM=128 (rows), BN=256 (full H), BK=32 x 8 double-buffered stages.
// A (=a1 tile) is computed on the fly and stored FRAGMENT-LINEAR in LDS:
//   stage buf = [g(8 row-groups of 16)][lane(64)][8 bf16], chunk for (g,lane):
//   A[row = g*16 + (lane&15)][k = s*32 + (lane>>4)*8 + b]
// -> all LDS writes/reads are lane-linear b128 (conflict-free), no swizzle.
__global__ __launch_bounds__(512, 4) void gemm_hcat(
    const float* __restrict__ x, const float* __restrict__ W1,
    const float* __restrict__ b1, const float* __restrict__ b2,
    const float* __restrict__ W3, const float* __restrict__ b3,
    const unsigned short* __restrict__ Bp, float* __restrict__ hcT) {
  __shared__ char As[2][8192];    // a1 stage dbuf
  __shared__ char Bs[2][16384];   // W2 stage dbuf
  __shared__ float P[4][128];     // cross-wave h partials (2 KB) -> 50 KB total

  int bid = blockIdx.x;
  int swz = (bid & 7) * 1024 + (bid >> 3);   // bijective XCD swizzle (8192 = 8*1024)
  int d = swz >> 7;
  int m0 = (swz & 127) << 7;

  int tid = threadIdx.x;
  int lane = tid & 63;
  int wid = tid >> 6;
  int wm = wid >> 2, wn = wid & 3;           // 2M x 4N waves, 64x64 per wave

  const unsigned short* BpD = Bp + (size_t)d * 65536;
  const float* W1d = W1 + d * Hn;
  const float* b1d = b1 + d * Hn;

  int arow = (wid << 4) + (lane & 15);       // this thread's a1 row (0..127)
  int koct = (lane >> 4) << 3;               // k-octet within stage (0,8,16,24)
  float xv = x[(size_t)(m0 + arow) * Dn + d];

  f32x4 acc[4][4] = {};

  // ---- stage helpers (fully inlined; s is a compile-time constant under unroll) ----
  #define DMA(s, b)                                                                   \
    {                                                                                 \
      _Pragma("unroll")                                                               \
      for (int j = 0; j < 2; ++j) {                                                   \
        const void* g = (const void*)(BpD + (((s) * 16 + wid * 2 + j) << 9) + (lane << 3)); \
        void* l = (void*)(Bs[b] + ((wid * 2 + j) << 10) + (lane << 4));               \
        __builtin_amdgcn_global_load_lds((const __attribute__((address_space(1))) void*)g, \
                                         (__attribute__((address_space(3))) void*)l, 16, 0, 0); \
      }                                                                               \
    }

  #define A1C(s, b)                                                                   \
    {                                                                                 \
      int k = (s) * 32 + koct;                                                        \
      float4 wa = *(const float4*)(W1d + k);                                          \
      float4 wb = *(const float4*)(W1d + k + 4);                                      \
      float4 ba = *(const float4*)(b1d + k);                                          \
      float4 bb = *(const float4*)(b1d + k + 4);                                      \
      float v0 = fmaxf(fmaf(xv, wa.x, ba.x), 0.f);                                    \
      float v1 = fmaxf(fmaf(xv, wa.y, ba.y), 0.f);                                    \
      float v2 = fmaxf(fmaf(xv, wa.z, ba.z), 0.f);                                    \
      float v3 = fmaxf(fmaf(xv, wa.w, ba.w), 0.f);                                    \
      float v4 = fmaxf(fmaf(xv, wb.x, bb.x), 0.f);                                    \
      float v5 = fmaxf(fmaf(xv, wb.y, bb.y), 0.f);                                    \
      float v6 = fmaxf(fmaf(xv, wb.z, bb.z), 0.f);                                    \
      float v7 = fmaxf(fmaf(xv, wb.w, bb.w), 0.f);                                    \
      uint4 pk;                                                                       \
      pk.x = ((__float_as_uint(v0) + 0x8000u) >> 16) | ((__float_as_uint(v1) + 0x8000u) & 0xFFFF0000u); \
      pk.y = ((__float_as_uint(v2) + 0x8000u) >> 16) | ((__float_as_uint(v3) + 0x8000u) & 0xFFFF0000u); \
      pk.z = ((__float_as_uint(v4) + 0x8000u) >> 16) | ((__float_as_uint(v5) + 0x8000u) & 0xFFFF0000u); \
      pk.w = ((__float_as_uint(v6) + 0x8000u) >> 16) | ((__float_as_uint(v7) + 0x8000u) & 0xFFFF0000u); \
      *(uint4*)(As[b] + (tid << 4)) = pk;                                             \
    }

  #define MM(b)                                                                       \
    {                                                                                 \
      bf16x8 bfr[4];                                                                  \
      _Pragma("unroll")                                                               \
      for (int nj = 0; nj < 4; ++nj)                                                  \
        bfr[nj] = *(const bf16x8*)(Bs[b] + ((((wn << 2) + nj) << 10) + (lane << 4))); \
      _Pragma("unroll")                                                               \
      for (int mi = 0; mi < 4; ++mi) {                                                \
        bf16x8 af = *(const bf16x8*)(As[b] + ((((wm << 2) + mi) << 10) + (lane << 4))); \
        _Pragma("unroll")                                                             \
        for (int nj = 0; nj < 4; ++nj)                                                \
          acc[mi][nj] = __builtin_amdgcn_mfma_f32_16x16x32_bf16(af, bfr[nj], acc[mi][nj], 0, 0, 0); \
      }                                                                               \
    }

  // prologue
  DMA(0, 0);
  A1C(0, 0);
  __syncthreads();

  #pragma unroll
  for (int s = 0; s < 8; ++s) {
    int cur = s & 1;
    if (s < 7) {
      DMA(s + 1, cur ^ 1);
      A1C(s + 1, cur ^ 1);
    }
    MM(cur);
    __syncthreads();   // also drains DMA + ds_writes (compiler emits waitcnt 0)
  }

  // epilogue: relu(+b2) . W3 over the 256 columns
  {
    const float* b2d = b2 + d * Hn;
    const float* W3d = W3 + d * Hn;
    float bv[4], wv[4];
    #pragma unroll
    for (int nj = 0; nj < 4; ++nj) {
      int col = ((wn << 2) + nj) * 16 + (lane & 15);
      bv[nj] = b2d[col];
      wv[nj] = W3d[col];
    }
    #pragma unroll
    for (int mi = 0; mi < 4; ++mi) {
      #pragma unroll
      for (int i = 0; i < 4; ++i) {
        float sv = 0.f;
        #pragma unroll
        for (int nj = 0; nj < 4; ++nj)
          sv += fmaxf(acc[mi][nj][i] + bv[nj], 0.f) * wv[nj];
        sv += __shfl_xor(sv, 1);
        sv += __shfl_xor(sv, 2);
        sv += __shfl_xor(sv, 4);
        sv += __shfl_xor(sv, 8);
        if ((lane & 15) == 0)
          P[wn][(wm << 6) + (mi << 4) + ((lane >> 4) << 2) + i] = sv;
      }
    }
  }
  __syncthreads();
  if (tid < 128)
    hcT[(size_t)d * Bn + m0 + tid] = P[0][tid] + P[1][tid] + P[2][tid] + P[3][tid] + b3[d];
}

// ---------- tail: attention fusion + cross MLP + g_func, one wave per row ----------
__global__ __launch_bounds__(256) void fused_tail(
    const float* __restrict__ hcT, const float* __restrict__ WqT,
    const float* __restrict__ bq, const float* __restrict__ WkT,
    const float* __restrict__ bk, const float* __restrict__ WsT,
    const float* __restrict__ bs, const float* __restrict__ Wc1T,
    const float* __restrict__ bc1, const float* __restrict__ Wc2,
    const float* __restrict__ bc2, const float* __restrict__ Wg1,
    const float* __restrict__ bg1, const float* __restrict__ Wg2,
    const float* __restrict__ bg2, float* __restrict__ out) {
  __shared__ float hcs[4][64];
  __shared__ float ts[4][256];
  int wid = threadIdx.x >> 6;
  int lane = threadIdx.x & 63;
  int row = blockIdx.x * 4 + wid;
  float hc = hcT[(size_t)lane * Bn + row];   // lane <-> feature d
  hcs[wid][lane] = hc;
  __syncthreads();
  float qv[4], kv[4], cv[4];
  #pragma unroll
  for (int j = 0; j < 4; ++j) {
    int h = lane + 64 * j;
    qv[j] = bq[h]; kv[j] = bk[h]; cv[j] = bc1[h];
  }
  for (int d2 = 0; d2 < 64; ++d2) {
    float hv = hcs[wid][d2];
    #pragma unroll
    for (int j = 0; j < 4; ++j) {
      int h = lane + 64 * j;
      qv[j] = fmaf(WqT[d2 * 256 + h], hv, qv[j]);
      kv[j] = fmaf(WkT[d2 * 256 + h], hv, kv[j]);
      cv[j] = fmaf(Wc1T[d2 * 256 + h], hv, cv[j]);
    }
  }
  #pragma unroll
  for (int j = 0; j < 4; ++j) ts[wid][lane + 64 * j] = tanhf(qv[j] * kv[j]);
  __syncthreads();
  float s0 = bs[lane], s1 = 0.f, s2 = 0.f, s3 = 0.f;
  for (int h2 = 0; h2 < 256; h2 += 4) {   // 4 partials break the dependent chain
    s0 = fmaf(WsT[(h2 + 0) * 64 + lane], ts[wid][h2 + 0], s0);
    s1 = fmaf(WsT[(h2 + 1) * 64 + lane], ts[wid][h2 + 1], s1);
    s2 = fmaf(WsT[(h2 + 2) * 64 + lane], ts[wid][h2 + 2], s2);
    s3 = fmaf(WsT[(h2 + 3) * 64 + lane], ts[wid][h2 + 3], s3);
  }
  float sc = (s0 + s1) + (s2 + s3);
  // softmax over the 64 features (one per lane)
  float mx = sc;
  #pragma unroll
  for (int off = 1; off < 64; off <<= 1) mx = fmaxf(mx, __shfl_xor(mx, off));
  float e = __expf(sc - mx);
  float se = e;
  #pragma unroll
  for (int off = 1; off < 64; off <<= 1) se += __shfl_xor(se, off);
  float wgt = hc * (e / se);
  #pragma unroll
  for (int off = 1; off < 64; off <<= 1) wgt += __shfl_xor(wgt, off);
  // cross MLP
  float cp = 0.f;
  #pragma unroll
  for (int j = 0; j < 4; ++j) {
    int h = lane + 64 * j;
    cp = fmaf(fmaxf(cv[j], 0.f), Wc2[h], cp);
  }
  #pragma unroll
  for (int off = 1; off < 64; off <<= 1) cp += __shfl_xor(cp, off);
  float comb = wgt + cp + bc2[0];
  // g_func
  float fp = 0.f;
  #pragma unroll
  for (int j = 0; j < 4; ++j) {
    int h = lane + 64 * j;
    fp = fmaf(fmaxf(fmaf(comb, Wg1[h], bg1[h]), 0.f), Wg2[h], fp);
  }
  #pragma unroll
  for (int off = 1; off < 64; off <<= 1) fp += __shfl_xor(fp, off);
  if (lane == 0) out[row] = fp + bg2[0];
}

extern "C" void kernel_launch(void* const* d_in, const int* in_sizes, int n_in,
                              void* d_out, int out_size, void* d_ws, size_t ws_size,
                              hipStream_t stream) {
  const float* x   = (const float*)d_in[0];
  const float* W1  = (const float*)d_in[1];
  const float* b1  = (const float*)d_in[2];
  const float* W2  = (const float*)d_in[3];
  const float* b2  = (const float*)d_in[4];
  const float* W3  = (const float*)d_in[5];
  const float* b3  = (const float*)d_in[6];
  const float* Wq  = (const float*)d_in[7];
  const float* bq  = (const float*)d_in[8];
  const float* Wk  = (const float*)d_in[9];
  const float* bk  = (const float*)d_in[10];
  const float* Ws  = (const float*)d_in[11];
  const float* bs  = (const float*)d_in[12];
  const float* Wc1 = (const float*)d_in[13];
  const float* bc1 = (const float*)d_in[14];
  const float* Wc2 = (const float*)d_in[15];
  const float* bc2 = (const float*)d_in[16];
  const float* Wg1 = (const float*)d_in[17];
  const float* bg1 = (const float*)d_in[18];
  const float* Wg2 = (const float*)d_in[19];
  const float* bg2 = (const float*)d_in[20];

  unsigned short* Bp = (unsigned short*)d_ws;               // 8,388,608 B
  float* hcT  = (float*)((char*)d_ws + 8388608);            // 4,194,304 B
  float* WqT  = (float*)((char*)d_ws + 12582912);
  float* WkT  = WqT + 16384;
  float* Wc1T = WkT + 16384;
  float* WsT  = Wc1T + 16384;

  pack_w2<<<2048, 256, 0, stream>>>(W2, Bp);
  prep_t<<<64, 256, 0, stream>>>(Wq, Wk, Wc1, Ws, WqT, WkT, Wc1T, WsT);
  gemm_hcat<<<8192, 512, 0, stream>>>(x, W1, b1, b2, W3, b3, Bp, hcT);
  fused_tail<<<4096, 256, 0, stream>>>(hcT, WqT, bq, WkT, bk, WsT, bs, Wc1T, bc1,
                                       Wc2, bc2, Wg1, bg1, Wg2, bg2, (float*)d_out);
}

// Round 3
// 245.176 us; speedup vs baseline: 2.3069x; 1.3092x over previous
//
#include <hip/hip_runtime.h>
#include <stdint.h>

#define Bn 16384
#define Dn 64
#define Hn 256

typedef short bf16x8 __attribute__((ext_vector_type(8)));
typedef float f32x4 __attribute__((ext_vector_type(4)));

__device__ __forceinline__ unsigned f2bf1(float f) {
  unsigned u = __float_as_uint(f);
  return (u + 0x7FFFu + ((u >> 16) & 1u)) >> 16;   // RNE to bf16
}

// ---------- pack W2 (fp32 [D][H][H]) into MFMA B-fragment-linear bf16 ----------
// layout: [d][kk(8)][nj(16)][lane(64)][8 bf16]; lane holds B[k=kk*32+(lane>>4)*8+b][n=nj*16+(lane&15)]
__global__ __launch_bounds__(256) void pack_w2(const float* __restrict__ W2,
                                               unsigned short* __restrict__ Bp) {
  int g = blockIdx.x * 4 + (threadIdx.x >> 6);   // 8192 units
  int lane = threadIdx.x & 63;
  int d  = g >> 7;
  int kk = (g >> 4) & 7;
  int nj = g & 15;
  int k0 = kk * 32 + ((lane >> 4) << 3);
  int n  = nj * 16 + (lane & 15);
  const float* src = W2 + ((size_t)d * Hn + k0) * Hn + n;
  unsigned t[8];
  #pragma unroll
  for (int b = 0; b < 8; ++b) t[b] = f2bf1(src[(size_t)b * Hn]);
  uint4 w;
  w.x = t[0] | (t[1] << 16);
  w.y = t[2] | (t[3] << 16);
  w.z = t[4] | (t[5] << 16);
  w.w = t[6] | (t[7] << 16);
  size_t off = (((size_t)g) * 64 + lane) * 8;    // elements
  *(uint4*)(Bp + off) = w;
}

// ---------- transpose small tail weights for coalesced reads ----------
__global__ __launch_bounds__(256) void prep_t(
    const float* __restrict__ Wq, const float* __restrict__ Wk,
    const float* __restrict__ Wc1, const float* __restrict__ Ws,
    float* __restrict__ WqT, float* __restrict__ WkT,
    float* __restrict__ Wc1T, float* __restrict__ WsT) {
  int t = blockIdx.x * 256 + threadIdx.x;   // 16384
  int h = t >> 6, dd = t & 63;
  WqT[dd * 256 + h]  = Wq[h * 64 + dd];
  WkT[dd * 256 + h]  = Wk[h * 64 + dd];
  Wc1T[dd * 256 + h] = Wc1[h * 64 + dd];
  WsT[h * 64 + dd]   = Ws[dd * 256 + h];
}

// ---------- main fused kernel: LDS-free, barrier-free K-loop ----------
// 256 threads = 4 waves (wn = 0..3), wave tile 64x64, BM=64, BN=256.
// A (a1) computed in registers from x,W1,b1 (rank-1). B fragments loaded
// directly global(L2) -> regs from the fragment-linear Bp, 1 stage prefetch.
__global__ __launch_bounds__(256, 4) void gemm_hcat(
    const float* __restrict__ x, const float* __restrict__ W1,
    const float* __restrict__ b1, const float* __restrict__ b2,
    const float* __restrict__ W3, const float* __restrict__ b3,
    const unsigned short* __restrict__ Bp, float* __restrict__ hcT) {
  __shared__ float P[4][64];

  int bid = blockIdx.x;
  int swz = (bid & 7) * 2048 + (bid >> 3);   // bijective XCD swizzle (16384 = 8*2048)
  int d = swz >> 8;
  int m0 = (swz & 255) << 6;

  int tid = threadIdx.x;
  int lane = tid & 63;
  int wn = tid >> 6;
  int l15 = lane & 15;
  int koct = (lane >> 4) << 3;

  const unsigned short* BpD = Bp + (size_t)d * 65536;
  const float* W1d = W1 + d * Hn;
  const float* b1d = b1 + d * Hn;

  float xr[4];
  #pragma unroll
  for (int mi = 0; mi < 4; ++mi)
    xr[mi] = x[(size_t)(m0 + mi * 16 + l15) * Dn + d];

  f32x4 acc[4][4] = {};

  #define LOADB(s, dst)                                                         \
    _Pragma("unroll")                                                           \
    for (int nj = 0; nj < 4; ++nj)                                              \
      dst[nj] = *(const bf16x8*)(BpD + (((((s) * 16 + (wn << 2) + nj)) << 6) + lane) * 8);

  bf16x8 bcur[4];
  LOADB(0, bcur);

  #pragma unroll
  for (int s = 0; s < 8; ++s) {
    bf16x8 bnxt[4];
    if (s < 7) { LOADB(s + 1, bnxt); }

    // a1 fragments in regs: af[mi][j] = bf16(relu(xr[mi]*W1[k+j]+b1[k+j]))
    int k = s * 32 + koct;
    float4 wa = *(const float4*)(W1d + k);
    float4 wb = *(const float4*)(W1d + k + 4);
    float4 ba = *(const float4*)(b1d + k);
    float4 bb = *(const float4*)(b1d + k + 4);
    bf16x8 af[4];
    #pragma unroll
    for (int mi = 0; mi < 4; ++mi) {
      float xv = xr[mi];
      unsigned u0 = __float_as_uint(fmaxf(fmaf(xv, wa.x, ba.x), 0.f)) + 0x8000u;
      unsigned u1 = __float_as_uint(fmaxf(fmaf(xv, wa.y, ba.y), 0.f)) + 0x8000u;
      unsigned u2 = __float_as_uint(fmaxf(fmaf(xv, wa.z, ba.z), 0.f)) + 0x8000u;
      unsigned u3 = __float_as_uint(fmaxf(fmaf(xv, wa.w, ba.w), 0.f)) + 0x8000u;
      unsigned u4 = __float_as_uint(fmaxf(fmaf(xv, wb.x, bb.x), 0.f)) + 0x8000u;
      unsigned u5 = __float_as_uint(fmaxf(fmaf(xv, wb.y, bb.y), 0.f)) + 0x8000u;
      unsigned u6 = __float_as_uint(fmaxf(fmaf(xv, wb.z, bb.z), 0.f)) + 0x8000u;
      unsigned u7 = __float_as_uint(fmaxf(fmaf(xv, wb.w, bb.w), 0.f)) + 0x8000u;
      union { uint4 u; bf16x8 v; } pk;
      pk.u.x = __builtin_amdgcn_perm(u1, u0, 0x07060302);   // hi16(u1):hi16(u0)
      pk.u.y = __builtin_amdgcn_perm(u3, u2, 0x07060302);
      pk.u.z = __builtin_amdgcn_perm(u5, u4, 0x07060302);
      pk.u.w = __builtin_amdgcn_perm(u7, u6, 0x07060302);
      af[mi] = pk.v;
    }

    #pragma unroll
    for (int mi = 0; mi < 4; ++mi)
      #pragma unroll
      for (int nj = 0; nj < 4; ++nj)
        acc[mi][nj] = __builtin_amdgcn_mfma_f32_16x16x32_bf16(af[mi], bcur[nj], acc[mi][nj], 0, 0, 0);

    if (s < 7) {
      #pragma unroll
      for (int nj = 0; nj < 4; ++nj) bcur[nj] = bnxt[nj];
    }
  }

  // epilogue: relu(+b2) . W3 over the 256 columns
  {
    const float* b2d = b2 + d * Hn;
    const float* W3d = W3 + d * Hn;
    float bv[4], wv[4];
    #pragma unroll
    for (int nj = 0; nj < 4; ++nj) {
      int col = ((wn << 2) + nj) * 16 + l15;
      bv[nj] = b2d[col];
      wv[nj] = W3d[col];
    }
    #pragma unroll
    for (int mi = 0; mi < 4; ++mi) {
      #pragma unroll
      for (int i = 0; i < 4; ++i) {
        float sv = 0.f;
        #pragma unroll
        for (int nj = 0; nj < 4; ++nj)
          sv += fmaxf(acc[mi][nj][i] + bv[nj], 0.f) * wv[nj];
        sv += __shfl_xor(sv, 1);
        sv += __shfl_xor(sv, 2);
        sv += __shfl_xor(sv, 4);
        sv += __shfl_xor(sv, 8);
        if (l15 == 0)
          P[wn][(mi << 4) + ((lane >> 4) << 2) + i] = sv;
      }
    }
  }
  __syncthreads();
  if (tid < 64)
    hcT[(size_t)d * Bn + m0 + tid] = P[0][tid] + P[1][tid] + P[2][tid] + P[3][tid] + b3[d];
}

// ---------- tail: attention fusion + cross MLP + g_func; 4 rows per wave ----------
__global__ __launch_bounds__(256) void fused_tail(
    const float* __restrict__ hcT, const float* __restrict__ WqT,
    const float* __restrict__ bq, const float* __restrict__ WkT,
    const float* __restrict__ bk, const float* __restrict__ WsT,
    const float* __restrict__ bs, const float* __restrict__ Wc1T,
    const float* __restrict__ bc1, const float* __restrict__ Wc2,
    const float* __restrict__ bc2, const float* __restrict__ Wg1,
    const float* __restrict__ bg1, const float* __restrict__ Wg2,
    const float* __restrict__ bg2, float* __restrict__ out) {
  __shared__ float hcs[4][4][64];
  __shared__ float ts[4][4][256];
  int wid = threadIdx.x >> 6;
  int lane = threadIdx.x & 63;
  int r0 = (blockIdx.x * 4 + wid) * 4;                 // 4 rows per wave
  float4 hc4 = *(const float4*)(hcT + (size_t)lane * Bn + r0);   // lane <-> feature d
  hcs[wid][0][lane] = hc4.x;
  hcs[wid][1][lane] = hc4.y;
  hcs[wid][2][lane] = hc4.z;
  hcs[wid][3][lane] = hc4.w;
  __syncthreads();

  float qv[4][4], kv[4][4], cv[4][4];
  #pragma unroll
  for (int j = 0; j < 4; ++j) {
    int h = lane + 64 * j;
    float bqv = bq[h], bkv = bk[h], bcv = bc1[h];
    #pragma unroll
    for (int r = 0; r < 4; ++r) { qv[r][j] = bqv; kv[r][j] = bkv; cv[r][j] = bcv; }
  }
  for (int d2 = 0; d2 < 64; ++d2) {
    float hv0 = hcs[wid][0][d2], hv1 = hcs[wid][1][d2];
    float hv2 = hcs[wid][2][d2], hv3 = hcs[wid][3][d2];
    #pragma unroll
    for (int j = 0; j < 4; ++j) {
      int h = lane + 64 * j;
      float wq = WqT[d2 * 256 + h], wk = WkT[d2 * 256 + h], wc = Wc1T[d2 * 256 + h];
      qv[0][j] = fmaf(wq, hv0, qv[0][j]); qv[1][j] = fmaf(wq, hv1, qv[1][j]);
      qv[2][j] = fmaf(wq, hv2, qv[2][j]); qv[3][j] = fmaf(wq, hv3, qv[3][j]);
      kv[0][j] = fmaf(wk, hv0, kv[0][j]); kv[1][j] = fmaf(wk, hv1, kv[1][j]);
      kv[2][j] = fmaf(wk, hv2, kv[2][j]); kv[3][j] = fmaf(wk, hv3, kv[3][j]);
      cv[0][j] = fmaf(wc, hv0, cv[0][j]); cv[1][j] = fmaf(wc, hv1, cv[1][j]);
      cv[2][j] = fmaf(wc, hv2, cv[2][j]); cv[3][j] = fmaf(wc, hv3, cv[3][j]);
    }
  }
  #pragma unroll
  for (int r = 0; r < 4; ++r)
    #pragma unroll
    for (int j = 0; j < 4; ++j)
      ts[wid][r][lane + 64 * j] = tanhf(qv[r][j] * kv[r][j]);
  __syncthreads();

  float sc[4];
  { float b = bs[lane]; sc[0] = b; sc[1] = b; sc[2] = b; sc[3] = b; }
  for (int h2 = 0; h2 < 256; ++h2) {
    float w = WsT[h2 * 64 + lane];
    sc[0] = fmaf(w, ts[wid][0][h2], sc[0]);
    sc[1] = fmaf(w, ts[wid][1][h2], sc[1]);
    sc[2] = fmaf(w, ts[wid][2][h2], sc[2]);
    sc[3] = fmaf(w, ts[wid][3][h2], sc[3]);
  }

  float hcr[4] = {hc4.x, hc4.y, hc4.z, hc4.w};
  float res[4];
  #pragma unroll
  for (int r = 0; r < 4; ++r) {
    float s = sc[r];
    float mx = s;
    #pragma unroll
    for (int off = 1; off < 64; off <<= 1) mx = fmaxf(mx, __shfl_xor(mx, off));
    float e = __expf(s - mx);
    float se = e;
    #pragma unroll
    for (int off = 1; off < 64; off <<= 1) se += __shfl_xor(se, off);
    float wgt = hcr[r] * (e / se);
    #pragma unroll
    for (int off = 1; off < 64; off <<= 1) wgt += __shfl_xor(wgt, off);
    float cp = 0.f;
    #pragma unroll
    for (int j = 0; j < 4; ++j) cp = fmaf(fmaxf(cv[r][j], 0.f), Wc2[lane + 64 * j], cp);
    #pragma unroll
    for (int off = 1; off < 64; off <<= 1) cp += __shfl_xor(cp, off);
    float comb = wgt + cp + bc2[0];
    float fp = 0.f;
    #pragma unroll
    for (int j = 0; j < 4; ++j) {
      int h = lane + 64 * j;
      fp = fmaf(fmaxf(fmaf(comb, Wg1[h], bg1[h]), 0.f), Wg2[h], fp);
    }
    #pragma unroll
    for (int off = 1; off < 64; off <<= 1) fp += __shfl_xor(fp, off);
    res[r] = fp + bg2[0];
  }
  if (lane == 0) {
    float4 o = make_float4(res[0], res[1], res[2], res[3]);
    *(float4*)(out + r0) = o;
  }
}

extern "C" void kernel_launch(void* const* d_in, const int* in_sizes, int n_in,
                              void* d_out, int out_size, void* d_ws, size_t ws_size,
                              hipStream_t stream) {
  const float* x   = (const float*)d_in[0];
  const float* W1  = (const float*)d_in[1];
  const float* b1  = (const float*)d_in[2];
  const float* W2  = (const float*)d_in[3];
  const float* b2  = (const float*)d_in[4];
  const float* W3  = (const float*)d_in[5];
  const float* b3  = (const float*)d_in[6];
  const float* Wq  = (const float*)d_in[7];
  const float* bq  = (const float*)d_in[8];
  const float* Wk  = (const float*)d_in[9];
  const float* bk  = (const float*)d_in[10];
  const float* Ws  = (const float*)d_in[11];
  const float* bs  = (const float*)d_in[12];
  const float* Wc1 = (const float*)d_in[13];
  const float* bc1 = (const float*)d_in[14];
  const float* Wc2 = (const float*)d_in[15];
  const float* bc2 = (const float*)d_in[16];
  const float* Wg1 = (const float*)d_in[17];
  const float* bg1 = (const float*)d_in[18];
  const float* Wg2 = (const float*)d_in[19];
  const float* bg2 = (const float*)d_in[20];

  unsigned short* Bp = (unsigned short*)d_ws;               // 8,388,608 B
  float* hcT  = (float*)((char*)d_ws + 8388608);            // 4,194,304 B
  float* WqT  = (float*)((char*)d_ws + 12582912);
  float* WkT  = WqT + 16384;
  float* Wc1T = WkT + 16384;
  float* WsT  = Wc1T + 16384;

  pack_w2<<<2048, 256, 0, stream>>>(W2, Bp);
  prep_t<<<64, 256, 0, stream>>>(Wq, Wk, Wc1, Ws, WqT, WkT, Wc1T, WsT);
  gemm_hcat<<<16384, 256, 0, stream>>>(x, W1, b1, b2, W3, b3, Bp, hcT);
  fused_tail<<<1024, 256, 0, stream>>>(hcT, WqT, bq, WkT, bk, WsT, bs, Wc1T, bc1,
                                       Wc2, bc2, Wg1, bg1, Wg2, bg2, (float*)d_out);
}